// Round 5
// baseline (18238.091 us; speedup 1.0000x reference)
//
#include <hip/hip_runtime.h>
#include <stdint.h>

#define T_STEPS 8192
#define DIN     2048
#define NH      256      // hidden size H
#define G4      1024     // 4*H
#define OUTW    2560     // DIN + 2*H

// ---------------------------------------------------------------- helpers
__device__ __forceinline__ float sigf(float x) {
    return 1.0f / (1.0f + __expf(-x));
}

__device__ __forceinline__ int dot4(int a, int b, int c) {
#if __has_builtin(__builtin_amdgcn_sdot4)
    return __builtin_amdgcn_sdot4(a, b, c, false);
#else
    int r = c;
#pragma unroll
    for (int i = 0; i < 4; ++i) {
        int ai = (a << (24 - 8 * i)) >> 24;
        int bi = (b << (24 - 8 * i)) >> 24;
        r += ai * bi;
    }
    return r;
#endif
}

// ---------------------------------------------------------------- quantize U
__global__ void quant_u_kernel(const float* __restrict__ U0, const float* __restrict__ U1,
                               const float* __restrict__ U2, const float* __restrict__ U3,
                               uint32_t* __restrict__ uq, float* __restrict__ sc) {
    const float* U = (blockIdx.x == 0) ? U0 : (blockIdx.x == 1) ? U1
                   : (blockIdx.x == 2) ? U2 : U3;
    uint32_t* uqo = uq + (size_t)blockIdx.x * (NH / 4) * G4;
    float* sco = sc + (size_t)blockIdx.x * G4;

    int j = threadIdx.x;  // one column per thread
    float ma = 0.f;
    for (int k = 0; k < NH; ++k) ma = fmaxf(ma, fabsf(U[(size_t)k * G4 + j]));
    float inv = (ma > 0.f) ? 127.f / ma : 0.f;
    sco[j] = ma * (1.0f / (127.f * 127.f));
    for (int w = 0; w < NH / 4; ++w) {
        uint32_t word = 0;
#pragma unroll
        for (int b = 0; b < 4; ++b) {
            float v = U[(size_t)(4 * w + b) * G4 + j];
            int q = __float2int_rn(v * inv);
            q = max(-127, min(127, q));
            word |= ((uint32_t)(q & 0xff)) << (8 * b);
        }
        uqo[(size_t)w * G4 + j] = word;
    }
}

// ---------------------------------------------------------------- copy x into both output slabs
__global__ void copy_x_kernel(const float4* __restrict__ x4, float* __restrict__ out) {
    const int total = 2 * T_STEPS * (DIN / 4);
    for (int i = blockIdx.x * blockDim.x + threadIdx.x; i < total;
         i += gridDim.x * blockDim.x) {
        int o   = i >> 22;
        int rem = i & ((1 << 22) - 1);
        int t   = rem >> 9;
        int c4  = rem & 511;
        float4 v = x4[(size_t)t * 512 + c4];
        *(float4*)(out + (size_t)o * T_STEPS * OUTW + (size_t)t * OUTW + (size_t)c4 * 4) = v;
    }
}

// ---------------------------------------------------------------- f32 tiled GEMM: C = A @ B + bias
__global__ __launch_bounds__(256) void gemm_zx_kernel(
    const float* __restrict__ A, int lda,
    const float* __restrict__ B, const float* __restrict__ bias,
    float* __restrict__ C, int K) {
    __shared__ float As[64][17];
    __shared__ float Bs[16][68];
    int tid = threadIdx.x;
    int bm = blockIdx.y * 64, bn = blockIdx.x * 64;
    int trow = tid >> 4, tcol = tid & 15;
    int ar = tid >> 2, ac = (tid & 3) * 4;
    int br = tid >> 4, bc = (tid & 15) * 4;
    float acc[4][4] = {};

    for (int k0 = 0; k0 < K; k0 += 16) {
        float4 av = *(const float4*)(A + (size_t)(bm + ar) * lda + k0 + ac);
        float4 bv = *(const float4*)(B + (size_t)(k0 + br) * G4 + bn + bc);
        As[ar][ac + 0] = av.x; As[ar][ac + 1] = av.y;
        As[ar][ac + 2] = av.z; As[ar][ac + 3] = av.w;
        Bs[br][bc + 0] = bv.x; Bs[br][bc + 1] = bv.y;
        Bs[br][bc + 2] = bv.z; Bs[br][bc + 3] = bv.w;
        __syncthreads();
#pragma unroll
        for (int kk = 0; kk < 16; ++kk) {
            float af[4], bf[4];
#pragma unroll
            for (int i = 0; i < 4; ++i) af[i] = As[trow * 4 + i][kk];
#pragma unroll
            for (int i = 0; i < 4; ++i) bf[i] = Bs[kk][tcol * 4 + i];
#pragma unroll
            for (int i = 0; i < 4; ++i)
#pragma unroll
                for (int j = 0; j < 4; ++j)
                    acc[i][j] = fmaf(af[i], bf[j], acc[i][j]);
        }
        __syncthreads();
    }
#pragma unroll
    for (int i = 0; i < 4; ++i) {
        float4 v;
        v.x = acc[i][0] + bias[bn + tcol * 4 + 0];
        v.y = acc[i][1] + bias[bn + tcol * 4 + 1];
        v.z = acc[i][2] + bias[bn + tcol * 4 + 2];
        v.w = acc[i][3] + bias[bn + tcol * 4 + 3];
        *(float4*)(C + (size_t)(bm + trow * 4 + i) * G4 + bn + tcol * 4) = v;
    }
}

// ---------------------------------------------------------------- sequential LSTM scan
// grid = 2 blocks (dir 0 = fwd, dir 1 = bwd), 1024 threads, EXACTLY 4 waves/EU
// (waves_per_eu(4,4) -> VGPR budget 128, so the 64 packed-U words stay resident).
// Phase 1 (all 1024 threads): z_j = zx_j + (U h)_j, s_j = sigmoid(z_j) -> LDS.
// Phase 2 (threads 0..255):   c = sf*c + si*sg; h = so*sigmoid(c) -> out + hq LDS.
__global__ __attribute__((amdgpu_flat_work_group_size(1024, 1024)))
__attribute__((amdgpu_waves_per_eu(4, 4))) void lstm_scan_kernel(
    const float* __restrict__ Zxf, const float* __restrict__ Zxb,
    const uint32_t* __restrict__ Uqf, const uint32_t* __restrict__ Uqb,
    const float* __restrict__ scf, const float* __restrict__ scb,
    float* __restrict__ outbase) {
    __shared__ float s_lds[G4];
    __shared__ int4 hq_lds4[16];  // 64 words = 256 int8 h values

    const int dir = blockIdx.x;
    const float* Zx = dir ? Zxb : Zxf;
    const uint32_t* Uq = dir ? Uqb : Uqf;
    const float* sc = dir ? scb : scf;

    const int j = threadIdx.x;   // one gate-column per thread

    // U column j into 64 VGPRs (int8 packed)
    int u[64];
#pragma unroll
    for (int w = 0; w < 64; ++w) u[w] = (int)Uq[(size_t)w * G4 + j];
    // forbid rematerialization of the loads inside the time loop
#pragma unroll
    for (int w = 0; w < 64; w += 4)
        asm volatile("" : "+v"(u[w]), "+v"(u[w + 1]), "+v"(u[w + 2]), "+v"(u[w + 3]));

    const float scj = sc[j];

    if (j < 16) hq_lds4[j] = make_int4(0, 0, 0, 0);
    float c = 0.f;

    const int step = dir ? -1 : 1;
    const int t0 = dir ? (T_STEPS - 1) : 0;
    // 2-deep Zx prefetch pipeline (HBM latency ~900cy > one step)
    float zx0 = Zx[(size_t)t0 * G4 + j];
    float zx1 = Zx[(size_t)(t0 + step) * G4 + j];
    float* outp = outbase + 2048 + dir * NH;
    __syncthreads();

    int t = t0;
    for (int s = 0; s < T_STEPS; ++s) {
        int t2 = t + 2 * step;
        t2 = (t2 < 0) ? 0 : (t2 >= T_STEPS ? T_STEPS - 1 : t2);
        const float zx2 = Zx[(size_t)t2 * G4 + j];

        int acc = 0;
#pragma unroll
        for (int w4 = 0; w4 < 16; ++w4) {
            const int4 hw = hq_lds4[w4];  // broadcast read
            acc = dot4(u[4 * w4 + 0], hw.x, acc);
            acc = dot4(u[4 * w4 + 1], hw.y, acc);
            acc = dot4(u[4 * w4 + 2], hw.z, acc);
            acc = dot4(u[4 * w4 + 3], hw.w, acc);
        }
        // every thread does its own sigmoid in parallel (1 exp across 16 waves)
        s_lds[j] = sigf(zx0 + (float)acc * scj);
        __syncthreads();

        if (j < NH) {
            float si = s_lds[j];
            float sf = s_lds[j + NH];
            float sg = s_lds[j + 2 * NH];
            float so = s_lds[j + 3 * NH];
            c = sf * c + si * sg;
            float h = so * sigf(c);
            outp[(size_t)t * OUTW + j] = h;
            int q = __float2int_rn(h * 127.f);
            q = max(0, min(127, q));
            ((uint8_t*)hq_lds4)[j] = (uint8_t)q;
        }
        __syncthreads();

        zx0 = zx1; zx1 = zx2;
        t += step;
    }
}

// ---------------------------------------------------------------- launch
extern "C" void kernel_launch(void* const* d_in, const int* in_sizes, int n_in,
                              void* d_out, int out_size, void* d_ws, size_t ws_size,
                              hipStream_t stream) {
    const float* x   = (const float*)d_in[0];
    const float* W1f = (const float*)d_in[1];
    const float* U1f = (const float*)d_in[2];
    const float* b1f = (const float*)d_in[3];
    const float* W1b = (const float*)d_in[4];
    const float* U1b = (const float*)d_in[5];
    const float* b1b = (const float*)d_in[6];
    const float* W2f = (const float*)d_in[7];
    const float* U2f = (const float*)d_in[8];
    const float* b2f = (const float*)d_in[9];
    const float* W2b = (const float*)d_in[10];
    const float* U2b = (const float*)d_in[11];
    const float* b2b = (const float*)d_in[12];

    float* out  = (float*)d_out;
    float* out1 = out + (size_t)T_STEPS * OUTW;

    // workspace layout
    float* Zxf = (float*)d_ws;
    float* Zxb = Zxf + (size_t)T_STEPS * G4;
    uint32_t* uq = (uint32_t*)(Zxb + (size_t)T_STEPS * G4);
    float* scq = (float*)(uq + (size_t)4 * 64 * G4);

    quant_u_kernel<<<4, 1024, 0, stream>>>(U1f, U1b, U2f, U2b, uq, scq);
    copy_x_kernel<<<2048, 256, 0, stream>>>((const float4*)x, out);

    dim3 gg(16, 128);
    gemm_zx_kernel<<<gg, 256, 0, stream>>>(x, DIN, W1f, b1f, Zxf, DIN);
    gemm_zx_kernel<<<gg, 256, 0, stream>>>(x, DIN, W1b, b1b, Zxb, DIN);

    lstm_scan_kernel<<<2, 1024, 0, stream>>>(Zxf, Zxb,
                                             uq + (size_t)0 * 64 * G4, uq + (size_t)1 * 64 * G4,
                                             scq + 0 * G4, scq + 1 * G4, out);

    gemm_zx_kernel<<<gg, 256, 0, stream>>>(out + 2048, OUTW, W2f, b2f, Zxf, 512);
    gemm_zx_kernel<<<gg, 256, 0, stream>>>(out + 2048, OUTW, W2b, b2b, Zxb, 512);

    lstm_scan_kernel<<<2, 1024, 0, stream>>>(Zxf, Zxb,
                                             uq + (size_t)2 * 64 * G4, uq + (size_t)3 * 64 * G4,
                                             scq + 2 * G4, scq + 3 * G4, out1);
}

// Round 6
// 18159.633 us; speedup vs baseline: 1.0043x; 1.0043x over previous
//
#include <hip/hip_runtime.h>
#include <stdint.h>

#define T_STEPS 8192
#define DIN     2048
#define NH      256      // hidden size H
#define G4      1024     // 4*H
#define OUTW    2560     // DIN + 2*H

// ---------------------------------------------------------------- helpers
__device__ __forceinline__ float sigf(float x) {
    return 1.0f / (1.0f + __expf(-x));
}

__device__ __forceinline__ int dot4(int a, int b, int c) {
#if __has_builtin(__builtin_amdgcn_sdot4)
    return __builtin_amdgcn_sdot4(a, b, c, false);
#else
    int r = c;
#pragma unroll
    for (int i = 0; i < 4; ++i) {
        int ai = (a << (24 - 8 * i)) >> 24;
        int bi = (b << (24 - 8 * i)) >> 24;
        r += ai * bi;
    }
    return r;
#endif
}

// ---------------------------------------------------------------- quantize U
// Layout for the scan: uq viewed as int4[16][1024]; entry [m][j] packs rows
// 4m..4m+3 (as 4 words each packing... see below) of column j.
// Precisely: word index (m*G4 + j)*4 + sub holds rows 4*(4m+sub)..4*(4m+sub)+3? NO:
// word (m*G4+j)*4+sub packs rows 4*(4*m+sub) is wrong too. Definition used:
//   logical word w (w=0..63) of column j packs rows 4w..4w+3;
//   stored at uq[(w>>2)*G4*4 + j*4 + (w&3)]  (so int4 m=w>>2 is contiguous).
__global__ void quant_u_kernel(const float* __restrict__ U0, const float* __restrict__ U1,
                               const float* __restrict__ U2, const float* __restrict__ U3,
                               uint32_t* __restrict__ uq, float* __restrict__ sc) {
    const float* U = (blockIdx.x == 0) ? U0 : (blockIdx.x == 1) ? U1
                   : (blockIdx.x == 2) ? U2 : U3;
    uint32_t* uqo = uq + (size_t)blockIdx.x * (NH / 4) * G4;
    float* sco = sc + (size_t)blockIdx.x * G4;

    int j = threadIdx.x;  // one column per thread
    float ma = 0.f;
    for (int k = 0; k < NH; ++k) ma = fmaxf(ma, fabsf(U[(size_t)k * G4 + j]));
    float inv = (ma > 0.f) ? 127.f / ma : 0.f;
    sco[j] = ma * (1.0f / (127.f * 127.f));
    for (int w = 0; w < NH / 4; ++w) {
        uint32_t word = 0;
#pragma unroll
        for (int b = 0; b < 4; ++b) {
            float v = U[(size_t)(4 * w + b) * G4 + j];
            int q = __float2int_rn(v * inv);
            q = max(-127, min(127, q));
            word |= ((uint32_t)(q & 0xff)) << (8 * b);
        }
        uqo[(size_t)(w >> 2) * G4 * 4 + (size_t)j * 4 + (w & 3)] = word;
    }
}

// ---------------------------------------------------------------- copy x into both output slabs
__global__ void copy_x_kernel(const float4* __restrict__ x4, float* __restrict__ out) {
    const int total = 2 * T_STEPS * (DIN / 4);
    for (int i = blockIdx.x * blockDim.x + threadIdx.x; i < total;
         i += gridDim.x * blockDim.x) {
        int o   = i >> 22;
        int rem = i & ((1 << 22) - 1);
        int t   = rem >> 9;
        int c4  = rem & 511;
        float4 v = x4[(size_t)t * 512 + c4];
        *(float4*)(out + (size_t)o * T_STEPS * OUTW + (size_t)t * OUTW + (size_t)c4 * 4) = v;
    }
}

// ---------------------------------------------------------------- f32 tiled GEMM: C = A @ B + bias
__global__ __launch_bounds__(256) void gemm_zx_kernel(
    const float* __restrict__ A, int lda,
    const float* __restrict__ B, const float* __restrict__ bias,
    float* __restrict__ C, int K) {
    __shared__ float As[64][17];
    __shared__ float Bs[16][68];
    int tid = threadIdx.x;
    int bm = blockIdx.y * 64, bn = blockIdx.x * 64;
    int trow = tid >> 4, tcol = tid & 15;
    int ar = tid >> 2, ac = (tid & 3) * 4;
    int br = tid >> 4, bc = (tid & 15) * 4;
    float acc[4][4] = {};

    for (int k0 = 0; k0 < K; k0 += 16) {
        float4 av = *(const float4*)(A + (size_t)(bm + ar) * lda + k0 + ac);
        float4 bv = *(const float4*)(B + (size_t)(k0 + br) * G4 + bn + bc);
        As[ar][ac + 0] = av.x; As[ar][ac + 1] = av.y;
        As[ar][ac + 2] = av.z; As[ar][ac + 3] = av.w;
        Bs[br][bc + 0] = bv.x; Bs[br][bc + 1] = bv.y;
        Bs[br][bc + 2] = bv.z; Bs[br][bc + 3] = bv.w;
        __syncthreads();
#pragma unroll
        for (int kk = 0; kk < 16; ++kk) {
            float af[4], bf[4];
#pragma unroll
            for (int i = 0; i < 4; ++i) af[i] = As[trow * 4 + i][kk];
#pragma unroll
            for (int i = 0; i < 4; ++i) bf[i] = Bs[kk][tcol * 4 + i];
#pragma unroll
            for (int i = 0; i < 4; ++i)
#pragma unroll
                for (int j = 0; j < 4; ++j)
                    acc[i][j] = fmaf(af[i], bf[j], acc[i][j]);
        }
        __syncthreads();
    }
#pragma unroll
    for (int i = 0; i < 4; ++i) {
        float4 v;
        v.x = acc[i][0] + bias[bn + tcol * 4 + 0];
        v.y = acc[i][1] + bias[bn + tcol * 4 + 1];
        v.z = acc[i][2] + bias[bn + tcol * 4 + 2];
        v.w = acc[i][3] + bias[bn + tcol * 4 + 3];
        *(float4*)(C + (size_t)(bm + trow * 4 + i) * G4 + bn + tcol * 4) = v;
    }
}

// ---------------------------------------------------------------- sequential LSTM scan
// grid = 2 blocks (dir 0 = fwd, dir 1 = bwd), 1024 threads, 4 waves/EU pinned.
// U column j lives in 16 NAMED int4 registers (no array -> no scratch demotion).
// Inner dot loop: 4 groups of {4 ds_read_b128 + 16 dot4} fenced by
// sched_barrier(0) so at most 4 h-words are live -> peak pressure ~100 < 128.
__global__ __attribute__((amdgpu_flat_work_group_size(1024, 1024)))
__attribute__((amdgpu_waves_per_eu(4, 4))) void lstm_scan_kernel(
    const float* __restrict__ Zxf, const float* __restrict__ Zxb,
    const uint32_t* __restrict__ Uqf, const uint32_t* __restrict__ Uqb,
    const float* __restrict__ scf, const float* __restrict__ scb,
    float* __restrict__ outbase) {
    __shared__ float s_lds[G4];
    __shared__ int4 hq_lds4[16];  // 64 words = 256 int8 h values

    const int dir = blockIdx.x;
    const float* Zx = dir ? Zxb : Zxf;
    const uint32_t* Uq = dir ? Uqb : Uqf;
    const float* sc = dir ? scb : scf;

    const int j = threadIdx.x;   // one gate-column per thread

    // 16 named int4 = 64 packed-U words for column j, coalesced dwordx4 loads
    const int4* Uq4 = (const int4*)Uq;
    int4 u0 = Uq4[0 * G4 + j],  u1 = Uq4[1 * G4 + j],  u2 = Uq4[2 * G4 + j],  u3 = Uq4[3 * G4 + j];
    int4 u4 = Uq4[4 * G4 + j],  u5 = Uq4[5 * G4 + j],  u6 = Uq4[6 * G4 + j],  u7 = Uq4[7 * G4 + j];
    int4 u8 = Uq4[8 * G4 + j],  u9 = Uq4[9 * G4 + j],  u10 = Uq4[10 * G4 + j], u11 = Uq4[11 * G4 + j];
    int4 u12 = Uq4[12 * G4 + j], u13 = Uq4[13 * G4 + j], u14 = Uq4[14 * G4 + j], u15 = Uq4[15 * G4 + j];
    // forbid re-sinking of these loads into the time loop
#define PIN4(v) asm volatile("" : "+v"(v.x), "+v"(v.y), "+v"(v.z), "+v"(v.w))
    PIN4(u0); PIN4(u1); PIN4(u2); PIN4(u3); PIN4(u4); PIN4(u5); PIN4(u6); PIN4(u7);
    PIN4(u8); PIN4(u9); PIN4(u10); PIN4(u11); PIN4(u12); PIN4(u13); PIN4(u14); PIN4(u15);
#undef PIN4

    const float scj = sc[j];

    if (j < 16) hq_lds4[j] = make_int4(0, 0, 0, 0);
    float c = 0.f;

    const int step = dir ? -1 : 1;
    const int t0 = dir ? (T_STEPS - 1) : 0;
    // 2-deep Zx prefetch pipeline (HBM latency ~900cy > one step)
    float zx0 = Zx[(size_t)t0 * G4 + j];
    float zx1 = Zx[(size_t)(t0 + step) * G4 + j];
    float* outp = outbase + 2048 + dir * NH;
    __syncthreads();

    int t = t0;
    for (int s = 0; s < T_STEPS; ++s) {
        int t2 = t + 2 * step;
        t2 = (t2 < 0) ? 0 : (t2 >= T_STEPS ? T_STEPS - 1 : t2);
        const float zx2 = Zx[(size_t)t2 * G4 + j];

        int acc = 0;
        // u int4 m pairs componentwise with hq_lds4[m] (word w=4m+c packs rows
        // 4w..4w+3; hq_lds4[m].c = packed h[16m+4c .. 16m+4c+3]).
#define DOTS(UM, HM) do { const int4 hh = (HM);                      \
            acc = dot4((UM).x, hh.x, acc); acc = dot4((UM).y, hh.y, acc); \
            acc = dot4((UM).z, hh.z, acc); acc = dot4((UM).w, hh.w, acc); } while (0)
        DOTS(u0, hq_lds4[0]);  DOTS(u1, hq_lds4[1]);
        DOTS(u2, hq_lds4[2]);  DOTS(u3, hq_lds4[3]);
        __builtin_amdgcn_sched_barrier(0);
        DOTS(u4, hq_lds4[4]);  DOTS(u5, hq_lds4[5]);
        DOTS(u6, hq_lds4[6]);  DOTS(u7, hq_lds4[7]);
        __builtin_amdgcn_sched_barrier(0);
        DOTS(u8, hq_lds4[8]);  DOTS(u9, hq_lds4[9]);
        DOTS(u10, hq_lds4[10]); DOTS(u11, hq_lds4[11]);
        __builtin_amdgcn_sched_barrier(0);
        DOTS(u12, hq_lds4[12]); DOTS(u13, hq_lds4[13]);
        DOTS(u14, hq_lds4[14]); DOTS(u15, hq_lds4[15]);
#undef DOTS

        // every thread does its own sigmoid in parallel (1 exp across 16 waves)
        s_lds[j] = sigf(zx0 + (float)acc * scj);
        __syncthreads();

        if (j < NH) {
            float si = s_lds[j];
            float sf = s_lds[j + NH];
            float sg = s_lds[j + 2 * NH];
            float so = s_lds[j + 3 * NH];
            c = sf * c + si * sg;
            float h = so * sigf(c);
            outp[(size_t)t * OUTW + j] = h;
            int q = __float2int_rn(h * 127.f);
            q = max(0, min(127, q));
            ((uint8_t*)hq_lds4)[j] = (uint8_t)q;
        }
        __syncthreads();

        zx0 = zx1; zx1 = zx2;
        t += step;
    }
}

// ---------------------------------------------------------------- launch
extern "C" void kernel_launch(void* const* d_in, const int* in_sizes, int n_in,
                              void* d_out, int out_size, void* d_ws, size_t ws_size,
                              hipStream_t stream) {
    const float* x   = (const float*)d_in[0];
    const float* W1f = (const float*)d_in[1];
    const float* U1f = (const float*)d_in[2];
    const float* b1f = (const float*)d_in[3];
    const float* W1b = (const float*)d_in[4];
    const float* U1b = (const float*)d_in[5];
    const float* b1b = (const float*)d_in[6];
    const float* W2f = (const float*)d_in[7];
    const float* U2f = (const float*)d_in[8];
    const float* b2f = (const float*)d_in[9];
    const float* W2b = (const float*)d_in[10];
    const float* U2b = (const float*)d_in[11];
    const float* b2b = (const float*)d_in[12];

    float* out  = (float*)d_out;
    float* out1 = out + (size_t)T_STEPS * OUTW;

    // workspace layout
    float* Zxf = (float*)d_ws;
    float* Zxb = Zxf + (size_t)T_STEPS * G4;
    uint32_t* uq = (uint32_t*)(Zxb + (size_t)T_STEPS * G4);
    float* scq = (float*)(uq + (size_t)4 * 64 * G4);

    quant_u_kernel<<<4, 1024, 0, stream>>>(U1f, U1b, U2f, U2b, uq, scq);
    copy_x_kernel<<<2048, 256, 0, stream>>>((const float4*)x, out);

    dim3 gg(16, 128);
    gemm_zx_kernel<<<gg, 256, 0, stream>>>(x, DIN, W1f, b1f, Zxf, DIN);
    gemm_zx_kernel<<<gg, 256, 0, stream>>>(x, DIN, W1b, b1b, Zxb, DIN);

    lstm_scan_kernel<<<2, 1024, 0, stream>>>(Zxf, Zxb,
                                             uq + (size_t)0 * 64 * G4, uq + (size_t)1 * 64 * G4,
                                             scq + 0 * G4, scq + 1 * G4, out);

    gemm_zx_kernel<<<gg, 256, 0, stream>>>(out + 2048, OUTW, W2f, b2f, Zxf, 512);
    gemm_zx_kernel<<<gg, 256, 0, stream>>>(out + 2048, OUTW, W2b, b2b, Zxb, 512);

    lstm_scan_kernel<<<2, 1024, 0, stream>>>(Zxf, Zxb,
                                             uq + (size_t)2 * 64 * G4, uq + (size_t)3 * 64 * G4,
                                             scq + 2 * G4, scq + 3 * G4, out1);
}

// Round 7
// 16275.653 us; speedup vs baseline: 1.1206x; 1.1158x over previous
//
#include <hip/hip_runtime.h>
#include <stdint.h>

#define T_STEPS 8192
#define DIN     2048
#define NH      256      // hidden size H
#define G4      1024     // 4*H
#define OUTW    2560     // DIN + 2*H

// ---------------------------------------------------------------- helpers
__device__ __forceinline__ float sigf(float x) {
    return 1.0f / (1.0f + __expf(-x));
}

__device__ __forceinline__ int dot4(int a, int b, int c) {
#if __has_builtin(__builtin_amdgcn_sdot4)
    return __builtin_amdgcn_sdot4(a, b, c, false);
#else
    int r = c;
#pragma unroll
    for (int i = 0; i < 4; ++i) {
        int ai = (a << (24 - 8 * i)) >> 24;
        int bi = (b << (24 - 8 * i)) >> 24;
        r += ai * bi;
    }
    return r;
#endif
}

// ---------------------------------------------------------------- quantize U
// Layout: logical word w (0..63) of column j packs rows 4w..4w+3 (int8 each);
// stored at uq[(w>>2)*G4*4 + j*4 + (w&3)] so each column's 4-word group m=w>>2
// is one contiguous int4 -> scan loads Uq4[m*G4 + j] with dwordx4.
__global__ void quant_u_kernel(const float* __restrict__ U0, const float* __restrict__ U1,
                               const float* __restrict__ U2, const float* __restrict__ U3,
                               uint32_t* __restrict__ uq, float* __restrict__ sc) {
    const float* U = (blockIdx.x == 0) ? U0 : (blockIdx.x == 1) ? U1
                   : (blockIdx.x == 2) ? U2 : U3;
    uint32_t* uqo = uq + (size_t)blockIdx.x * (NH / 4) * G4;
    float* sco = sc + (size_t)blockIdx.x * G4;

    int j = threadIdx.x;  // one column per thread
    float ma = 0.f;
    for (int k = 0; k < NH; ++k) ma = fmaxf(ma, fabsf(U[(size_t)k * G4 + j]));
    float inv = (ma > 0.f) ? 127.f / ma : 0.f;
    sco[j] = ma * (1.0f / (127.f * 127.f));
    for (int w = 0; w < NH / 4; ++w) {
        uint32_t word = 0;
#pragma unroll
        for (int b = 0; b < 4; ++b) {
            float v = U[(size_t)(4 * w + b) * G4 + j];
            int q = __float2int_rn(v * inv);
            q = max(-127, min(127, q));
            word |= ((uint32_t)(q & 0xff)) << (8 * b);
        }
        uqo[(size_t)(w >> 2) * G4 * 4 + (size_t)j * 4 + (w & 3)] = word;
    }
}

// ---------------------------------------------------------------- copy x into both output slabs
__global__ void copy_x_kernel(const float4* __restrict__ x4, float* __restrict__ out) {
    const int total = 2 * T_STEPS * (DIN / 4);
    for (int i = blockIdx.x * blockDim.x + threadIdx.x; i < total;
         i += gridDim.x * blockDim.x) {
        int o   = i >> 22;
        int rem = i & ((1 << 22) - 1);
        int t   = rem >> 9;
        int c4  = rem & 511;
        float4 v = x4[(size_t)t * 512 + c4];
        *(float4*)(out + (size_t)o * T_STEPS * OUTW + (size_t)t * OUTW + (size_t)c4 * 4) = v;
    }
}

// ---------------------------------------------------------------- f32 tiled GEMM: C = A @ B + bias
__global__ __launch_bounds__(256) void gemm_zx_kernel(
    const float* __restrict__ A, int lda,
    const float* __restrict__ B, const float* __restrict__ bias,
    float* __restrict__ C, int K) {
    __shared__ float As[64][17];
    __shared__ float Bs[16][68];
    int tid = threadIdx.x;
    int bm = blockIdx.y * 64, bn = blockIdx.x * 64;
    int trow = tid >> 4, tcol = tid & 15;
    int ar = tid >> 2, ac = (tid & 3) * 4;
    int br = tid >> 4, bc = (tid & 15) * 4;
    float acc[4][4] = {};

    for (int k0 = 0; k0 < K; k0 += 16) {
        float4 av = *(const float4*)(A + (size_t)(bm + ar) * lda + k0 + ac);
        float4 bv = *(const float4*)(B + (size_t)(k0 + br) * G4 + bn + bc);
        As[ar][ac + 0] = av.x; As[ar][ac + 1] = av.y;
        As[ar][ac + 2] = av.z; As[ar][ac + 3] = av.w;
        Bs[br][bc + 0] = bv.x; Bs[br][bc + 1] = bv.y;
        Bs[br][bc + 2] = bv.z; Bs[br][bc + 3] = bv.w;
        __syncthreads();
#pragma unroll
        for (int kk = 0; kk < 16; ++kk) {
            float af[4], bf[4];
#pragma unroll
            for (int i = 0; i < 4; ++i) af[i] = As[trow * 4 + i][kk];
#pragma unroll
            for (int i = 0; i < 4; ++i) bf[i] = Bs[kk][tcol * 4 + i];
#pragma unroll
            for (int i = 0; i < 4; ++i)
#pragma unroll
                for (int j = 0; j < 4; ++j)
                    acc[i][j] = fmaf(af[i], bf[j], acc[i][j]);
        }
        __syncthreads();
    }
#pragma unroll
    for (int i = 0; i < 4; ++i) {
        float4 v;
        v.x = acc[i][0] + bias[bn + tcol * 4 + 0];
        v.y = acc[i][1] + bias[bn + tcol * 4 + 1];
        v.z = acc[i][2] + bias[bn + tcol * 4 + 2];
        v.w = acc[i][3] + bias[bn + tcol * 4 + 3];
        *(float4*)(C + (size_t)(bm + trow * 4 + i) * G4 + bn + tcol * 4) = v;
    }
}

// ---------------------------------------------------------------- sequential LSTM scan
// grid = 2 blocks (dir 0 = fwd, dir 1 = bwd), 512 threads = 8 waves = 2 waves/EU
// pinned by waves_per_eu(2,2) -> 256-VGPR budget. Each thread owns columns
// j and j+512: 32 named int4 = 128 VGPRs of packed-U, plus worst-case 64 live
// h-word regs ~= 210 < 256 -> no spill-to-AGPR, no accvgpr_read tax.
__global__ __attribute__((amdgpu_flat_work_group_size(512, 512)))
__attribute__((amdgpu_waves_per_eu(2, 2))) void lstm_scan_kernel(
    const float* __restrict__ Zxf, const float* __restrict__ Zxb,
    const uint32_t* __restrict__ Uqf, const uint32_t* __restrict__ Uqb,
    const float* __restrict__ scf, const float* __restrict__ scb,
    float* __restrict__ outbase) {
    __shared__ float s_lds[G4];
    __shared__ int4 hq_lds4[16];  // 64 words = 256 int8 h values

    const int dir = blockIdx.x;
    const float* Zx = dir ? Zxb : Zxf;
    const uint32_t* Uq = dir ? Uqb : Uqf;
    const float* sc = dir ? scb : scf;

    const int j  = threadIdx.x;       // gate-column a
    const int j2 = threadIdx.x + 512; // gate-column b

    // 32 named int4 = 128 packed-U words for columns j and j+512
    const int4* Uq4 = (const int4*)Uq;
    int4 a0 = Uq4[0 * G4 + j],  a1 = Uq4[1 * G4 + j],  a2 = Uq4[2 * G4 + j],  a3 = Uq4[3 * G4 + j];
    int4 a4 = Uq4[4 * G4 + j],  a5 = Uq4[5 * G4 + j],  a6 = Uq4[6 * G4 + j],  a7 = Uq4[7 * G4 + j];
    int4 a8 = Uq4[8 * G4 + j],  a9 = Uq4[9 * G4 + j],  a10 = Uq4[10 * G4 + j], a11 = Uq4[11 * G4 + j];
    int4 a12 = Uq4[12 * G4 + j], a13 = Uq4[13 * G4 + j], a14 = Uq4[14 * G4 + j], a15 = Uq4[15 * G4 + j];
    int4 b0 = Uq4[0 * G4 + j2],  b1 = Uq4[1 * G4 + j2],  b2 = Uq4[2 * G4 + j2],  b3 = Uq4[3 * G4 + j2];
    int4 b4 = Uq4[4 * G4 + j2],  b5 = Uq4[5 * G4 + j2],  b6 = Uq4[6 * G4 + j2],  b7 = Uq4[7 * G4 + j2];
    int4 b8 = Uq4[8 * G4 + j2],  b9 = Uq4[9 * G4 + j2],  b10 = Uq4[10 * G4 + j2], b11 = Uq4[11 * G4 + j2];
    int4 b12 = Uq4[12 * G4 + j2], b13 = Uq4[13 * G4 + j2], b14 = Uq4[14 * G4 + j2], b15 = Uq4[15 * G4 + j2];
    // forbid re-sinking of these loads into the time loop
#define PIN4(v) asm volatile("" : "+v"(v.x), "+v"(v.y), "+v"(v.z), "+v"(v.w))
    PIN4(a0); PIN4(a1); PIN4(a2); PIN4(a3); PIN4(a4); PIN4(a5); PIN4(a6); PIN4(a7);
    PIN4(a8); PIN4(a9); PIN4(a10); PIN4(a11); PIN4(a12); PIN4(a13); PIN4(a14); PIN4(a15);
    PIN4(b0); PIN4(b1); PIN4(b2); PIN4(b3); PIN4(b4); PIN4(b5); PIN4(b6); PIN4(b7);
    PIN4(b8); PIN4(b9); PIN4(b10); PIN4(b11); PIN4(b12); PIN4(b13); PIN4(b14); PIN4(b15);
#undef PIN4

    const float sca = sc[j];
    const float scb2 = sc[j2];

    if (j < 16) hq_lds4[j] = make_int4(0, 0, 0, 0);
    float c = 0.f;

    const int step = dir ? -1 : 1;
    const int t0 = dir ? (T_STEPS - 1) : 0;
    // 2-deep Zx prefetch pipeline (HBM latency ~900cy > one step)
    float zxa0 = Zx[(size_t)t0 * G4 + j];
    float zxb0 = Zx[(size_t)t0 * G4 + j2];
    float zxa1 = Zx[(size_t)(t0 + step) * G4 + j];
    float zxb1 = Zx[(size_t)(t0 + step) * G4 + j2];
    float* outp = outbase + 2048 + dir * NH;
    __syncthreads();

    int t = t0;
    for (int s = 0; s < T_STEPS; ++s) {
        int t2 = t + 2 * step;
        t2 = (t2 < 0) ? 0 : (t2 >= T_STEPS ? T_STEPS - 1 : t2);
        const float zxa2 = Zx[(size_t)t2 * G4 + j];
        const float zxb2 = Zx[(size_t)t2 * G4 + j2];

        int acca = 0, accb = 0;
        // int4 group m pairs componentwise with hq_lds4[m]; dual acc chains
#define DOTS2(UA, UB, HM) do { const int4 hh = (HM);                        \
            acca = dot4((UA).x, hh.x, acca); accb = dot4((UB).x, hh.x, accb); \
            acca = dot4((UA).y, hh.y, acca); accb = dot4((UB).y, hh.y, accb); \
            acca = dot4((UA).z, hh.z, acca); accb = dot4((UB).z, hh.z, accb); \
            acca = dot4((UA).w, hh.w, acca); accb = dot4((UB).w, hh.w, accb); } while (0)
        DOTS2(a0, b0, hq_lds4[0]);   DOTS2(a1, b1, hq_lds4[1]);
        DOTS2(a2, b2, hq_lds4[2]);   DOTS2(a3, b3, hq_lds4[3]);
        DOTS2(a4, b4, hq_lds4[4]);   DOTS2(a5, b5, hq_lds4[5]);
        DOTS2(a6, b6, hq_lds4[6]);   DOTS2(a7, b7, hq_lds4[7]);
        DOTS2(a8, b8, hq_lds4[8]);   DOTS2(a9, b9, hq_lds4[9]);
        DOTS2(a10, b10, hq_lds4[10]); DOTS2(a11, b11, hq_lds4[11]);
        DOTS2(a12, b12, hq_lds4[12]); DOTS2(a13, b13, hq_lds4[13]);
        DOTS2(a14, b14, hq_lds4[14]); DOTS2(a15, b15, hq_lds4[15]);
#undef DOTS2

        // per-column sigmoid in parallel across all 8 waves
        s_lds[j]  = sigf(zxa0 + (float)acca * sca);
        s_lds[j2] = sigf(zxb0 + (float)accb * scb2);
        __syncthreads();

        if (j < NH) {
            float si = s_lds[j];
            float sf = s_lds[j + NH];
            float sg = s_lds[j + 2 * NH];
            float so = s_lds[j + 3 * NH];
            c = sf * c + si * sg;
            float h = so * sigf(c);
            outp[(size_t)t * OUTW + j] = h;
            int q = __float2int_rn(h * 127.f);
            q = max(0, min(127, q));
            ((uint8_t*)hq_lds4)[j] = (uint8_t)q;
        }
        __syncthreads();

        zxa0 = zxa1; zxa1 = zxa2;
        zxb0 = zxb1; zxb1 = zxb2;
        t += step;
    }
}

// ---------------------------------------------------------------- launch
extern "C" void kernel_launch(void* const* d_in, const int* in_sizes, int n_in,
                              void* d_out, int out_size, void* d_ws, size_t ws_size,
                              hipStream_t stream) {
    const float* x   = (const float*)d_in[0];
    const float* W1f = (const float*)d_in[1];
    const float* U1f = (const float*)d_in[2];
    const float* b1f = (const float*)d_in[3];
    const float* W1b = (const float*)d_in[4];
    const float* U1b = (const float*)d_in[5];
    const float* b1b = (const float*)d_in[6];
    const float* W2f = (const float*)d_in[7];
    const float* U2f = (const float*)d_in[8];
    const float* b2f = (const float*)d_in[9];
    const float* W2b = (const float*)d_in[10];
    const float* U2b = (const float*)d_in[11];
    const float* b2b = (const float*)d_in[12];

    float* out  = (float*)d_out;
    float* out1 = out + (size_t)T_STEPS * OUTW;

    // workspace layout
    float* Zxf = (float*)d_ws;
    float* Zxb = Zxf + (size_t)T_STEPS * G4;
    uint32_t* uq = (uint32_t*)(Zxb + (size_t)T_STEPS * G4);
    float* scq = (float*)(uq + (size_t)4 * 64 * G4);

    quant_u_kernel<<<4, 1024, 0, stream>>>(U1f, U1b, U2f, U2b, uq, scq);
    copy_x_kernel<<<2048, 256, 0, stream>>>((const float4*)x, out);

    dim3 gg(16, 128);
    gemm_zx_kernel<<<gg, 256, 0, stream>>>(x, DIN, W1f, b1f, Zxf, DIN);
    gemm_zx_kernel<<<gg, 256, 0, stream>>>(x, DIN, W1b, b1b, Zxb, DIN);

    lstm_scan_kernel<<<2, 512, 0, stream>>>(Zxf, Zxb,
                                            uq + (size_t)0 * 64 * G4, uq + (size_t)1 * 64 * G4,
                                            scq + 0 * G4, scq + 1 * G4, out);

    gemm_zx_kernel<<<gg, 256, 0, stream>>>(out + 2048, OUTW, W2f, b2f, Zxf, 512);
    gemm_zx_kernel<<<gg, 256, 0, stream>>>(out + 2048, OUTW, W2b, b2b, Zxb, 512);

    lstm_scan_kernel<<<2, 512, 0, stream>>>(Zxf, Zxb,
                                            uq + (size_t)2 * 64 * G4, uq + (size_t)3 * 64 * G4,
                                            scq + 2 * G4, scq + 3 * G4, out1);
}